// Round 9
// baseline (197.760 us; speedup 1.0000x reference)
//
#include <hip/hip_runtime.h>

#define D 64
#define CHUNK 4096      // edges per partition block
#define BSHIFT 8        // bucket = dst >> 8 (256 nodes per bucket)

typedef unsigned int uint;
typedef unsigned short ushort;

using bf16x8 = __attribute__((ext_vector_type(8))) short;   // 8 bf16 (4 VGPRs)
using f32x4  = __attribute__((ext_vector_type(4))) float;   // 4 fp32 acc

// fp32 -> bf16 round-to-nearest-even (finite inputs)
__device__ __forceinline__ uint f2bf(float f) {
    uint u = __float_as_uint(f);
    return (u + 0x7fffu + ((u >> 16) & 1u)) >> 16;
}
__device__ __forceinline__ uint pk2(float a, float b) {
    return f2bf(a) | (f2bf(b) << 16);
}

// masked accumulate: acc += mk * decode(v)  (uint4 = 8 packed bf16)
#define ACC8M(v, aE, aO, mk) do {                                              \
    aE[0] = fmaf(mk, __uint_as_float((v).x << 16), aE[0]);                     \
    aO[0] = fmaf(mk, __uint_as_float((v).x & 0xffff0000u), aO[0]);             \
    aE[1] = fmaf(mk, __uint_as_float((v).y << 16), aE[1]);                     \
    aO[1] = fmaf(mk, __uint_as_float((v).y & 0xffff0000u), aO[1]);             \
    aE[2] = fmaf(mk, __uint_as_float((v).z << 16), aE[2]);                     \
    aO[2] = fmaf(mk, __uint_as_float((v).z & 0xffff0000u), aO[2]);             \
    aE[3] = fmaf(mk, __uint_as_float((v).w << 16), aE[3]);                     \
    aO[3] = fmaf(mk, __uint_as_float((v).w & 0xffff0000u), aO[3]);             \
} while (0)

// ---------------------------------------------------------------------------
// MFMA 2-layer MLP tile: one wave computes 16 nodes of
// out = relu(relu(X@W1+b1)@W2+b2) with 16x16x32 bf16 MFMAs.
//   A-frag:  lane holds A[m=lane&15][k=quad*8+j]
//   B-frag:  lane holds B[k=quad*8+j][n=lane&15]
//   C/D:     lane holds D[row=quad*4+reg][col=lane&15]
// H C->A layout via LDS (stride 72 shorts: conflict-free).
// ---------------------------------------------------------------------------
template <bool BF16IN, bool BF16OUT>
__device__ __forceinline__ void mlp_tile(
    int tile, ushort (*Hs)[72],
    const float* __restrict__ Xf, const ushort* __restrict__ Xb,
    const float* __restrict__ W1, const float* __restrict__ b1v,
    const float* __restrict__ W2, const float* __restrict__ b2v,
    ushort* __restrict__ out16, float* __restrict__ out32, int N)
{
    const int lane = threadIdx.x & 63;
    const int m = lane & 15;
    const int q = lane >> 4;

    // weight B-frags (bf16, VGPR-resident)
    bf16x8 w1f[4][2], w2f[4][2];
    #pragma unroll
    for (int t = 0; t < 4; ++t) {
        const int n = t * 16 + m;
        #pragma unroll
        for (int kf = 0; kf < 2; ++kf) {
            bf16x8 f1, f2;
            #pragma unroll
            for (int j = 0; j < 8; ++j) {
                const int k = kf * 32 + q * 8 + j;
                f1[j] = (short)f2bf(W1[k * D + n]);
                f2[j] = (short)f2bf(W2[k * D + n]);
            }
            w1f[t][kf] = f1;
            w2f[t][kf] = f2;
        }
    }

    // X A-frags
    const int rowbase = tile * 16;
    int r = rowbase + m;
    if (r >= N) r = N - 1;               // clamp loads; stores predicated
    bf16x8 ax0, ax1;
    if (BF16IN) {
        const ushort* xr = Xb + (size_t)r * D + q * 8;
        ax0 = *(const bf16x8*)xr;
        ax1 = *(const bf16x8*)(xr + 32);
    } else {
        const float* xr = Xf + (size_t)r * D + q * 8;
        float4 x0 = *(const float4*)xr;
        float4 x1 = *(const float4*)(xr + 4);
        float4 x2 = *(const float4*)(xr + 32);
        float4 x3 = *(const float4*)(xr + 36);
        ax0[0]=(short)f2bf(x0.x); ax0[1]=(short)f2bf(x0.y);
        ax0[2]=(short)f2bf(x0.z); ax0[3]=(short)f2bf(x0.w);
        ax0[4]=(short)f2bf(x1.x); ax0[5]=(short)f2bf(x1.y);
        ax0[6]=(short)f2bf(x1.z); ax0[7]=(short)f2bf(x1.w);
        ax1[0]=(short)f2bf(x2.x); ax1[1]=(short)f2bf(x2.y);
        ax1[2]=(short)f2bf(x2.z); ax1[3]=(short)f2bf(x2.w);
        ax1[4]=(short)f2bf(x3.x); ax1[5]=(short)f2bf(x3.y);
        ax1[6]=(short)f2bf(x3.z); ax1[7]=(short)f2bf(x3.w);
    }

    const f32x4 zero4 = {0.f, 0.f, 0.f, 0.f};
    f32x4 acc[4];

    // layer 1
    #pragma unroll
    for (int t = 0; t < 4; ++t) acc[t] = zero4;
    #pragma unroll
    for (int t = 0; t < 4; ++t) {
        acc[t] = __builtin_amdgcn_mfma_f32_16x16x32_bf16(ax0, w1f[t][0], acc[t], 0, 0, 0);
        acc[t] = __builtin_amdgcn_mfma_f32_16x16x32_bf16(ax1, w1f[t][1], acc[t], 0, 0, 0);
    }
    #pragma unroll
    for (int t = 0; t < 4; ++t) {
        const float bv = b1v[t * 16 + m];
        #pragma unroll
        for (int rg = 0; rg < 4; ++rg) {
            float hv = fmaxf(acc[t][rg] + bv, 0.f);
            Hs[q * 4 + rg][t * 16 + m] = (ushort)f2bf(hv);
        }
    }
    __syncthreads();

    // H C-layout -> A-frags
    bf16x8 ah0 = *(const bf16x8*)&Hs[m][q * 8];
    bf16x8 ah1 = *(const bf16x8*)&Hs[m][32 + q * 8];

    // layer 2
    #pragma unroll
    for (int t = 0; t < 4; ++t) acc[t] = zero4;
    #pragma unroll
    for (int t = 0; t < 4; ++t) {
        acc[t] = __builtin_amdgcn_mfma_f32_16x16x32_bf16(ah0, w2f[t][0], acc[t], 0, 0, 0);
        acc[t] = __builtin_amdgcn_mfma_f32_16x16x32_bf16(ah1, w2f[t][1], acc[t], 0, 0, 0);
    }
    #pragma unroll
    for (int t = 0; t < 4; ++t) {
        const float bv = b2v[t * 16 + m];
        #pragma unroll
        for (int rg = 0; rg < 4; ++rg) {
            const int row = rowbase + q * 4 + rg;
            if (row < N) {
                float ov = fmaxf(acc[t][rg] + bv, 0.f);
                if (BF16OUT) out16[(size_t)row * D + t * 16 + m] = (ushort)f2bf(ov);
                else         out32[(size_t)row * D + t * 16 + m] = ov;
            }
        }
    }
}

// ---------------------------------------------------------------------------
// kA: blocks [0,NBA): per-chunk bucket histogram (LDS only)
//     blocks [NBA,...): message MLP (MFMA), msg stored bf16.
// ---------------------------------------------------------------------------
__global__ __launch_bounds__(256) void kA_mlp_hist(
    const float* __restrict__ y,
    const float* __restrict__ W1, const float* __restrict__ b1,
    const float* __restrict__ W2, const float* __restrict__ b2,
    ushort* __restrict__ msg16, int N,
    const int* __restrict__ dst, int* __restrict__ histG, int E, int NBA)
{
    __shared__ __align__(16) ushort Hs[4][16][72];
    __shared__ int lhist[256];
    const int t = threadIdx.x;
    if ((int)blockIdx.x < NBA) {
        lhist[t] = 0;
        __syncthreads();
        const int cbase = blockIdx.x * CHUNK;
        const int lim = min(CHUNK, E - cbase);
        for (int j = t; j < lim; j += 256)
            atomicAdd(&lhist[(uint)dst[cbase + j] >> BSHIFT], 1);
        __syncthreads();
        histG[blockIdx.x * 256 + t] = lhist[t];
    } else {
        const int tile = (blockIdx.x - NBA) * 4 + (t >> 6);
        mlp_tile<false, true>(tile, Hs[t >> 6], y, nullptr, W1, b1, W2, b2,
                              msg16, nullptr, N);
    }
}

// ---------------------------------------------------------------------------
// kC: partition edges into bucket-grouped packedG. Each block derives its own
// per-(chunk,bucket) cursor from histG (column sums + prefix) — kB fused out.
// Block 0 also publishes tot[bucket].
// ---------------------------------------------------------------------------
__global__ __launch_bounds__(256) void kC_partition(
    const int* __restrict__ src, const int* __restrict__ dst,
    const int* __restrict__ histG, int* __restrict__ tot_out,
    uint* __restrict__ packedG, int E, int NBA)
{
    __shared__ int t1[256];
    __shared__ int cur[256];
    const int t = threadIdx.x;
    const int blk = blockIdx.x;

    // column t of histG: total over all chunks + prefix over chunks < blk
    int before = 0, total = 0;
    for (int c = 0; c < NBA; ++c) {
        int h = histG[c * 256 + t];
        total += h;
        before += (c < blk) ? h : 0;
    }
    if (blk == 0) tot_out[t] = total;

    // exclusive scan of bucket totals
    int x = total; t1[t] = x; __syncthreads();
    #pragma unroll
    for (int off = 1; off < 256; off <<= 1) {
        int add = (t >= off) ? t1[t - off] : 0; __syncthreads();
        x += add; t1[t] = x; __syncthreads();
    }
    cur[t] = (x - total) + before;
    __syncthreads();

    const int cbase = blk * CHUNK;
    const int lim = min(CHUNK, E - cbase);
    for (int j = t; j < lim; j += 256) {
        const int e = cbase + j;
        int s = src[e], d = dst[e];
        int pos = atomicAdd(&cur[(uint)d >> BSHIFT], 1);
        packedG[pos] = ((uint)(d & 255) << 16) | (uint)s;
    }
}

// ---------------------------------------------------------------------------
// kF: one block per bucket. Pass 1: per-node counts via LDS atomics.
// Scan -> absolute offsets[node]. Pass 2: place entries node-grouped into
// sortedG (single-writer bucket region -> L2 merges the 2B writes).
// ---------------------------------------------------------------------------
__global__ __launch_bounds__(256) void kF_place(
    const uint* __restrict__ packedG, const int* __restrict__ tot,
    ushort* __restrict__ sortedG, int* __restrict__ offsets, int N, int E)
{
    __shared__ int t1[256];
    __shared__ int cnt[256];
    __shared__ int cur[256];
    const int t = threadIdx.x;
    const int b = blockIdx.x;

    int tv = tot[t];
    int x = tv; t1[t] = x; __syncthreads();
    #pragma unroll
    for (int off = 1; off < 256; off <<= 1) {
        int add = (t >= off) ? t1[t - off] : 0; __syncthreads();
        x += add; t1[t] = x; __syncthreads();
    }
    const int pbase = (b == 0) ? 0 : t1[b - 1];
    const int cn = tot[b];

    cnt[t] = 0;
    __syncthreads();
    for (int i = t; i < cn; i += 256)
        atomicAdd(&cnt[packedG[pbase + i] >> 16], 1);
    __syncthreads();

    int c = cnt[t];
    int x2 = c; t1[t] = x2; __syncthreads();
    #pragma unroll
    for (int off = 1; off < 256; off <<= 1) {
        int add = (t >= off) ? t1[t - off] : 0; __syncthreads();
        x2 += add; t1[t] = x2; __syncthreads();
    }
    const int excl = x2 - c;
    cur[t] = pbase + excl;
    const int node = b * 256 + t;
    if (node < N) offsets[node] = pbase + excl;
    if (b == 0 && t == 0) offsets[N] = E;
    __syncthreads();

    for (int i = t; i < cn; i += 256) {
        uint e = packedG[pbase + i];
        int p = atomicAdd(&cur[e >> 16], 1);
        sortedG[p] = (ushort)(e & 0xffffu);
    }
}

// ---------------------------------------------------------------------------
// k5: gather segment-sum (bf16 msg) -> z bf16. TWO nodes per wave:
//   sub  = lane&7       : 16B slice of the 128B row
//   grp  = (lane>>3)&3  : one of 4 edges per step
//   half = lane>>5      : which node of the pair
// Up to 8 steps (32 edges/node) issued fully before any decode; masked fma
// handles tails; outer loop covers deg>32. One pair per wave.
// ---------------------------------------------------------------------------
__global__ __launch_bounds__(256, 6) void k5_gather(
    const ushort* __restrict__ msg16,
    const int* __restrict__ offsets, const ushort* __restrict__ sortedG,
    ushort* __restrict__ z16, int n_nodes)
{
    const int lane = threadIdx.x & 63;
    const int sub = lane & 7;
    const int grp = (lane >> 3) & 3;
    const int half = lane >> 5;
    const int p = blockIdx.x * 4 + (threadIdx.x >> 6);   // pair index
    if (p * 2 >= n_nodes) return;
    const ushort* mbase = msg16 + (sub << 3);

    const int n = 2 * p + half;                          // per-lane node
    const bool nvalid = n < n_nodes;
    int beg = 0, end = 0;
    if (nvalid) { beg = offsets[n]; end = offsets[n + 1]; }
    const int m = end - beg;
    const int m0 = __builtin_amdgcn_readfirstlane(m);    // half0 degree
    const int m1 = __builtin_amdgcn_readlane(m, 32);     // half1 degree
    const int mmax = max(m0, m1);                        // wave-uniform

    float aE[4] = {0, 0, 0, 0}, aO[4] = {0, 0, 0, 0};

    for (int base = 0; base < mmax; base += 32) {
        int s[8];
        float mk[8];
        #pragma unroll
        for (int j = 0; j < 8; ++j) {
            if (base + j * 4 < mmax) {                   // uniform guard
                const int e = base + j * 4 + grp;
                const bool on = (e < m);                 // per-lane mask
                mk[j] = on ? 1.f : 0.f;
                s[j] = (int)sortedG[on ? (beg + e) : 0];
            }
        }
        uint4 v[8];
        #pragma unroll
        for (int j = 0; j < 8; ++j)                      // all rows in flight
            if (base + j * 4 < mmax)
                v[j] = *(const uint4*)(mbase + ((size_t)s[j] << 6));
        #pragma unroll
        for (int j = 0; j < 8; ++j)
            if (base + j * 4 < mmax) { ACC8M(v[j], aE, aO, mk[j]); }
    }

    #pragma unroll
    for (int d2 = 0; d2 < 4; ++d2) {   // reduce over grp (lane bits 3,4 only)
        aE[d2] += __shfl_xor(aE[d2], 8, 64);
        aO[d2] += __shfl_xor(aO[d2], 8, 64);
        aE[d2] += __shfl_xor(aE[d2], 16, 64);
        aO[d2] += __shfl_xor(aO[d2], 16, 64);
    }
    if (grp == 0 && nvalid) {          // lanes 0-7 & 32-39: 16B each
        uint4 pv;
        pv.x = pk2(aE[0], aO[0]);
        pv.y = pk2(aE[1], aO[1]);
        pv.z = pk2(aE[2], aO[2]);
        pv.w = pk2(aE[3], aO[3]);
        *(uint4*)(z16 + (size_t)n * D + (sub << 3)) = pv;
    }
}

// ---------------------------------------------------------------------------
// mlp2: update MLP (MFMA): z16 bf16 -> out fp32
// ---------------------------------------------------------------------------
__global__ __launch_bounds__(256) void k_mlp2(
    const ushort* __restrict__ z16,
    const float* __restrict__ U1, const float* __restrict__ c1,
    const float* __restrict__ U2, const float* __restrict__ c2,
    float* __restrict__ out, int N)
{
    __shared__ __align__(16) ushort Hs[4][16][72];
    const int tile = blockIdx.x * 4 + (threadIdx.x >> 6);
    mlp_tile<true, false>(tile, Hs[threadIdx.x >> 6], nullptr, z16,
                          U1, c1, U2, c2, nullptr, out, N);
}

extern "C" void kernel_launch(void* const* d_in, const int* in_sizes, int n_in,
                              void* d_out, int out_size, void* d_ws, size_t ws_size,
                              hipStream_t stream) {
    const float* y  = (const float*)d_in[0];
    const int*  src = (const int*) d_in[1];
    const int*  dst = (const int*) d_in[2];
    const float* W1 = (const float*)d_in[3];
    const float* b1 = (const float*)d_in[4];
    const float* W2 = (const float*)d_in[5];
    const float* b2 = (const float*)d_in[6];
    const float* U1 = (const float*)d_in[7];
    const float* c1 = (const float*)d_in[8];
    const float* U2 = (const float*)d_in[9];
    const float* c2 = (const float*)d_in[10];

    const int N = in_sizes[0] / D;               // 50000
    const int E = in_sizes[1];                   // 1250000
    const int NBA   = (E + CHUNK - 1) / CHUNK;   // 306 partition chunks
    const int NBUCK = (N + 255) / 256;           // 196 buckets
    const int NT    = (N + 15) / 16;             // 3125 MFMA row-tiles
    const int MB    = (NT + 3) / 4;              // 782 MLP blocks
    const int GB    = (N / 2 + 4 * 256 - 1) / (4 * 256) * 256 / 256; // pairs/4 waves
    const int G5    = (N / 2 + 3) / 4;           // k5 blocks: 1 pair per wave

    // Workspace layout (z16 aliases hist/partition scratch, dead by k5)
    char* ws = (char*)d_ws;
    auto al16 = [](size_t x) { return (x + 15) & ~15ull; };
    ushort* msg16   = (ushort*)ws;  ws += al16((size_t)N * D * 2);
    int*    offsets = (int*)ws;     ws += al16((size_t)(N + 1) * 4);
    int*    tot     = (int*)ws;     ws += al16(256 * 4);
    ushort* sortedG = (ushort*)ws;  ws += al16((size_t)E * 2);
    // overlap region: max(histG+packedG, z16)
    ushort* z16     = (ushort*)ws;                     // N*D bf16 (6.4 MB)
    int*    histG   = (int*)ws;                        // NBA*256 ints
    uint*   packedG = (uint*)(histG + (size_t)NBA * 256);  // E uints
    (void)GB;

    // 1) fused: message MLP (MFMA) + per-chunk bucket histogram
    kA_mlp_hist<<<NBA + MB, 256, 0, stream>>>(
        y, W1, b1, W2, b2, msg16, N, dst, histG, E, NBA);

    // 2) partition edges into bucket-grouped packedG (kB fused in)
    kC_partition<<<NBA, 256, 0, stream>>>(src, dst, histG, tot, packedG, E, NBA);

    // 3) per-bucket counting sort -> sortedG + absolute offsets
    kF_place<<<NBUCK, 256, 0, stream>>>(packedG, tot, sortedG, offsets, N, E);

    // 4) gather segment-sum -> z16 (2 nodes per wave)
    k5_gather<<<G5, 256, 0, stream>>>(msg16, offsets, sortedG, z16, N);

    // 5) update MLP (MFMA) -> out
    k_mlp2<<<MB, 256, 0, stream>>>(z16, U1, c1, U2, c2, (float*)d_out, N);
}

// Round 10
// 149.106 us; speedup vs baseline: 1.3263x; 1.3263x over previous
//
#include <hip/hip_runtime.h>

#define D 64
#define CHUNK 4096      // edges per partition block
#define BSHIFT 8        // bucket = dst >> 8 (256 nodes per bucket)
#define MAXB 8192       // max edges per bucket for LDS-staged sort

typedef unsigned int uint;
typedef unsigned short ushort;

using bf16x8 = __attribute__((ext_vector_type(8))) short;   // 8 bf16 (4 VGPRs)
using f32x4  = __attribute__((ext_vector_type(4))) float;   // 4 fp32 acc

// fp32 -> bf16 round-to-nearest-even (finite inputs)
__device__ __forceinline__ uint f2bf(float f) {
    uint u = __float_as_uint(f);
    return (u + 0x7fffu + ((u >> 16) & 1u)) >> 16;
}
__device__ __forceinline__ uint pk2(float a, float b) {
    return f2bf(a) | (f2bf(b) << 16);
}

// masked accumulate: acc += mk * decode(v)  (uint4 = 8 packed bf16)
#define ACC8M(v, aE, aO, mk) do {                                              \
    aE[0] = fmaf(mk, __uint_as_float((v).x << 16), aE[0]);                     \
    aO[0] = fmaf(mk, __uint_as_float((v).x & 0xffff0000u), aO[0]);             \
    aE[1] = fmaf(mk, __uint_as_float((v).y << 16), aE[1]);                     \
    aO[1] = fmaf(mk, __uint_as_float((v).y & 0xffff0000u), aO[1]);             \
    aE[2] = fmaf(mk, __uint_as_float((v).z << 16), aE[2]);                     \
    aO[2] = fmaf(mk, __uint_as_float((v).z & 0xffff0000u), aO[2]);             \
    aE[3] = fmaf(mk, __uint_as_float((v).w << 16), aE[3]);                     \
    aO[3] = fmaf(mk, __uint_as_float((v).w & 0xffff0000u), aO[3]);             \
} while (0)

// ---------------------------------------------------------------------------
// MFMA 2-layer MLP tile: one wave computes 16 nodes of
// out = relu(relu(X@W1+b1)@W2+b2) with 16x16x32 bf16 MFMAs.
//   A-frag:  lane holds A[m=lane&15][k=quad*8+j]
//   B-frag:  lane holds B[k=quad*8+j][n=lane&15]
//   C/D:     lane holds D[row=quad*4+reg][col=lane&15]
// H C->A layout via LDS (stride 72 shorts: conflict-free).
// ---------------------------------------------------------------------------
template <bool BF16IN, bool BF16OUT>
__device__ __forceinline__ void mlp_tile(
    int tile, ushort (*Hs)[72],
    const float* __restrict__ Xf, const ushort* __restrict__ Xb,
    const float* __restrict__ W1, const float* __restrict__ b1v,
    const float* __restrict__ W2, const float* __restrict__ b2v,
    ushort* __restrict__ out16, float* __restrict__ out32, int N)
{
    const int lane = threadIdx.x & 63;
    const int m = lane & 15;
    const int q = lane >> 4;

    // weight B-frags (bf16, VGPR-resident)
    bf16x8 w1f[4][2], w2f[4][2];
    #pragma unroll
    for (int t = 0; t < 4; ++t) {
        const int n = t * 16 + m;
        #pragma unroll
        for (int kf = 0; kf < 2; ++kf) {
            bf16x8 f1, f2;
            #pragma unroll
            for (int j = 0; j < 8; ++j) {
                const int k = kf * 32 + q * 8 + j;
                f1[j] = (short)f2bf(W1[k * D + n]);
                f2[j] = (short)f2bf(W2[k * D + n]);
            }
            w1f[t][kf] = f1;
            w2f[t][kf] = f2;
        }
    }

    // X A-frags
    const int rowbase = tile * 16;
    int r = rowbase + m;
    if (r >= N) r = N - 1;               // clamp loads; stores predicated
    bf16x8 ax0, ax1;
    if (BF16IN) {
        const ushort* xr = Xb + (size_t)r * D + q * 8;
        ax0 = *(const bf16x8*)xr;
        ax1 = *(const bf16x8*)(xr + 32);
    } else {
        const float* xr = Xf + (size_t)r * D + q * 8;
        float4 x0 = *(const float4*)xr;
        float4 x1 = *(const float4*)(xr + 4);
        float4 x2 = *(const float4*)(xr + 32);
        float4 x3 = *(const float4*)(xr + 36);
        ax0[0]=(short)f2bf(x0.x); ax0[1]=(short)f2bf(x0.y);
        ax0[2]=(short)f2bf(x0.z); ax0[3]=(short)f2bf(x0.w);
        ax0[4]=(short)f2bf(x1.x); ax0[5]=(short)f2bf(x1.y);
        ax0[6]=(short)f2bf(x1.z); ax0[7]=(short)f2bf(x1.w);
        ax1[0]=(short)f2bf(x2.x); ax1[1]=(short)f2bf(x2.y);
        ax1[2]=(short)f2bf(x2.z); ax1[3]=(short)f2bf(x2.w);
        ax1[4]=(short)f2bf(x3.x); ax1[5]=(short)f2bf(x3.y);
        ax1[6]=(short)f2bf(x3.z); ax1[7]=(short)f2bf(x3.w);
    }

    const f32x4 zero4 = {0.f, 0.f, 0.f, 0.f};
    f32x4 acc[4];

    // layer 1
    #pragma unroll
    for (int t = 0; t < 4; ++t) acc[t] = zero4;
    #pragma unroll
    for (int t = 0; t < 4; ++t) {
        acc[t] = __builtin_amdgcn_mfma_f32_16x16x32_bf16(ax0, w1f[t][0], acc[t], 0, 0, 0);
        acc[t] = __builtin_amdgcn_mfma_f32_16x16x32_bf16(ax1, w1f[t][1], acc[t], 0, 0, 0);
    }
    #pragma unroll
    for (int t = 0; t < 4; ++t) {
        const float bv = b1v[t * 16 + m];
        #pragma unroll
        for (int rg = 0; rg < 4; ++rg) {
            float hv = fmaxf(acc[t][rg] + bv, 0.f);
            Hs[q * 4 + rg][t * 16 + m] = (ushort)f2bf(hv);
        }
    }
    __syncthreads();

    // H C-layout -> A-frags
    bf16x8 ah0 = *(const bf16x8*)&Hs[m][q * 8];
    bf16x8 ah1 = *(const bf16x8*)&Hs[m][32 + q * 8];

    // layer 2
    #pragma unroll
    for (int t = 0; t < 4; ++t) acc[t] = zero4;
    #pragma unroll
    for (int t = 0; t < 4; ++t) {
        acc[t] = __builtin_amdgcn_mfma_f32_16x16x32_bf16(ah0, w2f[t][0], acc[t], 0, 0, 0);
        acc[t] = __builtin_amdgcn_mfma_f32_16x16x32_bf16(ah1, w2f[t][1], acc[t], 0, 0, 0);
    }
    #pragma unroll
    for (int t = 0; t < 4; ++t) {
        const float bv = b2v[t * 16 + m];
        #pragma unroll
        for (int rg = 0; rg < 4; ++rg) {
            const int row = rowbase + q * 4 + rg;
            if (row < N) {
                float ov = fmaxf(acc[t][rg] + bv, 0.f);
                if (BF16OUT) out16[(size_t)row * D + t * 16 + m] = (ushort)f2bf(ov);
                else         out32[(size_t)row * D + t * 16 + m] = ov;
            }
        }
    }
}

// ---------------------------------------------------------------------------
// kA: blocks [0,NBA): per-chunk bucket histogram (LDS only, int4-batched)
//     blocks [NBA,...): message MLP (MFMA), msg stored bf16.
// ---------------------------------------------------------------------------
__global__ __launch_bounds__(256) void kA_mlp_hist(
    const float* __restrict__ y,
    const float* __restrict__ W1, const float* __restrict__ b1,
    const float* __restrict__ W2, const float* __restrict__ b2,
    ushort* __restrict__ msg16, int N,
    const int* __restrict__ dst, int* __restrict__ histG, int E, int NBA)
{
    __shared__ __align__(16) ushort Hs[4][16][72];
    __shared__ int lhist[256];
    const int t = threadIdx.x;
    if ((int)blockIdx.x < NBA) {
        lhist[t] = 0;
        __syncthreads();
        const int cbase = blockIdx.x * CHUNK;
        const int lim = min(CHUNK, E - cbase);
        if (lim == CHUNK) {
            // 16 edges/thread: 4 coalesced int4 loads, then 16 LDS atomics
            const int4* dp = (const int4*)(dst + cbase);
            int4 d4[4];
            #pragma unroll
            for (int g = 0; g < 4; ++g) d4[g] = dp[g * 256 + t];
            #pragma unroll
            for (int g = 0; g < 4; ++g) {
                atomicAdd(&lhist[(uint)d4[g].x >> BSHIFT], 1);
                atomicAdd(&lhist[(uint)d4[g].y >> BSHIFT], 1);
                atomicAdd(&lhist[(uint)d4[g].z >> BSHIFT], 1);
                atomicAdd(&lhist[(uint)d4[g].w >> BSHIFT], 1);
            }
        } else {
            for (int j = t; j < lim; j += 256)
                atomicAdd(&lhist[(uint)dst[cbase + j] >> BSHIFT], 1);
        }
        __syncthreads();
        histG[blockIdx.x * 256 + t] = lhist[t];
    } else {
        const int tile = (blockIdx.x - NBA) * 4 + (t >> 6);
        mlp_tile<false, true>(tile, Hs[t >> 6], y, nullptr, W1, b1, W2, b2,
                              msg16, nullptr, N);
    }
}

// ---------------------------------------------------------------------------
// kB: one block per bucket: exclusive scan over the NBA chunk histograms
//     -> startG[(chunk,bucket)], tot[bucket].  (NBA <= 512)
// ---------------------------------------------------------------------------
__global__ __launch_bounds__(256) void kB_scan(
    const int* __restrict__ histG, int* __restrict__ startG,
    int* __restrict__ tot, int NBA)
{
    __shared__ int tmp[256];
    const int t = threadIdx.x;
    const int b = blockIdx.x;
    const int i0 = 2 * t, i1 = 2 * t + 1;
    int v0 = (i0 < NBA) ? histG[i0 * 256 + b] : 0;
    int v1 = (i1 < NBA) ? histG[i1 * 256 + b] : 0;
    int s = v0 + v1;
    int x = s; tmp[t] = x; __syncthreads();
    #pragma unroll
    for (int off = 1; off < 256; off <<= 1) {
        int add = (t >= off) ? tmp[t - off] : 0; __syncthreads();
        x += add; tmp[t] = x; __syncthreads();
    }
    int excl = x - s;
    if (i0 < NBA) startG[i0 * 256 + b] = excl;
    if (i1 < NBA) startG[i1 * 256 + b] = excl + v0;
    if (t == 255) tot[b] = x;
}

// ---------------------------------------------------------------------------
// kC: partition edges into bucket-grouped packedG at per-(chunk,bucket)
// contiguous runs. int4-batched: 16 edges/thread loaded upfront.
// ---------------------------------------------------------------------------
__global__ __launch_bounds__(256) void kC_partition(
    const int* __restrict__ src, const int* __restrict__ dst,
    const int* __restrict__ startG, const int* __restrict__ tot,
    uint* __restrict__ packedG, int E)
{
    __shared__ int t1[256];
    __shared__ int cur[256];
    const int t = threadIdx.x;
    int tv = tot[t];
    int x = tv; t1[t] = x; __syncthreads();
    #pragma unroll
    for (int off = 1; off < 256; off <<= 1) {
        int add = (t >= off) ? t1[t - off] : 0; __syncthreads();
        x += add; t1[t] = x; __syncthreads();
    }
    cur[t] = (x - tv) + startG[blockIdx.x * 256 + t];
    __syncthreads();
    const int cbase = blockIdx.x * CHUNK;
    const int lim = min(CHUNK, E - cbase);
    if (lim == CHUNK) {
        const int4* sp = (const int4*)(src + cbase);
        const int4* dp = (const int4*)(dst + cbase);
        int4 s4[4], d4[4];
        #pragma unroll
        for (int g = 0; g < 4; ++g) { s4[g] = sp[g * 256 + t]; d4[g] = dp[g * 256 + t]; }
        #pragma unroll
        for (int g = 0; g < 4; ++g) {
            int pos;
            pos = atomicAdd(&cur[(uint)d4[g].x >> BSHIFT], 1);
            packedG[pos] = ((uint)(d4[g].x & 255) << 16) | (uint)s4[g].x;
            pos = atomicAdd(&cur[(uint)d4[g].y >> BSHIFT], 1);
            packedG[pos] = ((uint)(d4[g].y & 255) << 16) | (uint)s4[g].y;
            pos = atomicAdd(&cur[(uint)d4[g].z >> BSHIFT], 1);
            packedG[pos] = ((uint)(d4[g].z & 255) << 16) | (uint)s4[g].z;
            pos = atomicAdd(&cur[(uint)d4[g].w >> BSHIFT], 1);
            packedG[pos] = ((uint)(d4[g].w & 255) << 16) | (uint)s4[g].w;
        }
    } else {
        for (int j = t; j < lim; j += 256) {
            const int e = cbase + j;
            int s = src[e], d = dst[e];
            int pos = atomicAdd(&cur[(uint)d >> BSHIFT], 1);
            packedG[pos] = ((uint)(d & 255) << 16) | (uint)s;
        }
    }
}

// ---------------------------------------------------------------------------
// kF: one block per bucket. Stage the bucket's packedG region in LDS once
// (coalesced read), count+scan+place in LDS, write sortedG coalesced.
// Fallback to the global 2-pass path if the bucket exceeds MAXB.
// ---------------------------------------------------------------------------
__global__ __launch_bounds__(256) void kF_place(
    const uint* __restrict__ packedG, const int* __restrict__ tot,
    ushort* __restrict__ sortedG, int* __restrict__ offsets, int N, int E)
{
    __shared__ int t1[256];
    __shared__ int cnt[256];
    __shared__ int cur[256];
    __shared__ uint pk[MAXB];      // 32 KB
    __shared__ ushort srt[MAXB];   // 16 KB
    const int t = threadIdx.x;
    const int b = blockIdx.x;

    int tv = tot[t];
    int x = tv; t1[t] = x; __syncthreads();
    #pragma unroll
    for (int off = 1; off < 256; off <<= 1) {
        int add = (t >= off) ? t1[t - off] : 0; __syncthreads();
        x += add; t1[t] = x; __syncthreads();
    }
    const int pbase = (b == 0) ? 0 : t1[b - 1];
    const int cn = tot[b];
    const bool fits = (cn <= MAXB);

    cnt[t] = 0;
    __syncthreads();
    if (fits) {
        for (int i = t; i < cn; i += 256) pk[i] = packedG[pbase + i];
        __syncthreads();
        for (int i = t; i < cn; i += 256) atomicAdd(&cnt[pk[i] >> 16], 1);
    } else {
        for (int i = t; i < cn; i += 256)
            atomicAdd(&cnt[packedG[pbase + i] >> 16], 1);
    }
    __syncthreads();

    int c = cnt[t];
    int x2 = c; t1[t] = x2; __syncthreads();
    #pragma unroll
    for (int off = 1; off < 256; off <<= 1) {
        int add = (t >= off) ? t1[t - off] : 0; __syncthreads();
        x2 += add; t1[t] = x2; __syncthreads();
    }
    const int excl = x2 - c;
    const int node = b * 256 + t;
    if (node < N) offsets[node] = pbase + excl;
    if (b == 0 && t == 0) offsets[N] = E;

    if (fits) {
        cur[t] = excl;                       // local positions
        __syncthreads();
        for (int i = t; i < cn; i += 256) {
            uint e = pk[i];
            int p = atomicAdd(&cur[e >> 16], 1);
            srt[p] = (ushort)(e & 0xffffu);
        }
        __syncthreads();
        for (int i = t; i < cn; i += 256)    // coalesced write-out
            sortedG[pbase + i] = srt[i];
    } else {
        cur[t] = pbase + excl;
        __syncthreads();
        for (int i = t; i < cn; i += 256) {
            uint e = packedG[pbase + i];
            int p = atomicAdd(&cur[e >> 16], 1);
            sortedG[p] = (ushort)(e & 0xffffu);
        }
    }
}

// ---------------------------------------------------------------------------
// k5: gather segment-sum (bf16 msg) -> z bf16. TWO nodes per wave:
//   sub  = lane&7       : 16B slice of the 128B row
//   grp  = (lane>>3)&3  : one of 4 edges per step
//   half = lane>>5      : which node of the pair
// Up to 8 steps (32 edges/node) issued fully before any decode; masked fma
// handles tails; outer loop covers deg>32.
// ---------------------------------------------------------------------------
__global__ __launch_bounds__(256, 6) void k5_gather(
    const ushort* __restrict__ msg16,
    const int* __restrict__ offsets, const ushort* __restrict__ sortedG,
    ushort* __restrict__ z16, int n_nodes)
{
    const int lane = threadIdx.x & 63;
    const int sub = lane & 7;
    const int grp = (lane >> 3) & 3;
    const int half = lane >> 5;
    const int p = blockIdx.x * 4 + (threadIdx.x >> 6);   // pair index
    if (p * 2 >= n_nodes) return;
    const ushort* mbase = msg16 + (sub << 3);

    const int n = 2 * p + half;                          // per-lane node
    const bool nvalid = n < n_nodes;
    int beg = 0, end = 0;
    if (nvalid) { beg = offsets[n]; end = offsets[n + 1]; }
    const int m = end - beg;
    const int m0 = __builtin_amdgcn_readfirstlane(m);    // half0 degree
    const int m1 = __builtin_amdgcn_readlane(m, 32);     // half1 degree
    const int mmax = max(m0, m1);                        // wave-uniform

    float aE[4] = {0, 0, 0, 0}, aO[4] = {0, 0, 0, 0};

    for (int base = 0; base < mmax; base += 32) {
        int s[8];
        float mk[8];
        #pragma unroll
        for (int j = 0; j < 8; ++j) {
            if (base + j * 4 < mmax) {                   // uniform guard
                const int e = base + j * 4 + grp;
                const bool on = (e < m);                 // per-lane mask
                mk[j] = on ? 1.f : 0.f;
                s[j] = (int)sortedG[on ? (beg + e) : 0];
            }
        }
        uint4 v[8];
        #pragma unroll
        for (int j = 0; j < 8; ++j)                      // all rows in flight
            if (base + j * 4 < mmax)
                v[j] = *(const uint4*)(mbase + ((size_t)s[j] << 6));
        #pragma unroll
        for (int j = 0; j < 8; ++j)
            if (base + j * 4 < mmax) { ACC8M(v[j], aE, aO, mk[j]); }
    }

    #pragma unroll
    for (int d2 = 0; d2 < 4; ++d2) {   // reduce over grp (lane bits 3,4 only)
        aE[d2] += __shfl_xor(aE[d2], 8, 64);
        aO[d2] += __shfl_xor(aO[d2], 8, 64);
        aE[d2] += __shfl_xor(aE[d2], 16, 64);
        aO[d2] += __shfl_xor(aO[d2], 16, 64);
    }
    if (grp == 0 && nvalid) {          // lanes 0-7 & 32-39: 16B each
        uint4 pv;
        pv.x = pk2(aE[0], aO[0]);
        pv.y = pk2(aE[1], aO[1]);
        pv.z = pk2(aE[2], aO[2]);
        pv.w = pk2(aE[3], aO[3]);
        *(uint4*)(z16 + (size_t)n * D + (sub << 3)) = pv;
    }
}

// ---------------------------------------------------------------------------
// mlp2: update MLP (MFMA): z16 bf16 -> out fp32
// ---------------------------------------------------------------------------
__global__ __launch_bounds__(256) void k_mlp2(
    const ushort* __restrict__ z16,
    const float* __restrict__ U1, const float* __restrict__ c1,
    const float* __restrict__ U2, const float* __restrict__ c2,
    float* __restrict__ out, int N)
{
    __shared__ __align__(16) ushort Hs[4][16][72];
    const int tile = blockIdx.x * 4 + (threadIdx.x >> 6);
    mlp_tile<true, false>(tile, Hs[threadIdx.x >> 6], nullptr, z16,
                          U1, c1, U2, c2, nullptr, out, N);
}

extern "C" void kernel_launch(void* const* d_in, const int* in_sizes, int n_in,
                              void* d_out, int out_size, void* d_ws, size_t ws_size,
                              hipStream_t stream) {
    const float* y  = (const float*)d_in[0];
    const int*  src = (const int*) d_in[1];
    const int*  dst = (const int*) d_in[2];
    const float* W1 = (const float*)d_in[3];
    const float* b1 = (const float*)d_in[4];
    const float* W2 = (const float*)d_in[5];
    const float* b2 = (const float*)d_in[6];
    const float* U1 = (const float*)d_in[7];
    const float* c1 = (const float*)d_in[8];
    const float* U2 = (const float*)d_in[9];
    const float* c2 = (const float*)d_in[10];

    const int N = in_sizes[0] / D;               // 50000
    const int E = in_sizes[1];                   // 1250000
    const int NBA   = (E + CHUNK - 1) / CHUNK;   // 306 partition chunks (<=512)
    const int NBUCK = (N + 255) / 256;           // 196 buckets
    const int NT    = (N + 15) / 16;             // 3125 MFMA row-tiles
    const int MB    = (NT + 3) / 4;              // 782 MLP blocks
    const int G5    = (N / 2 + 3) / 4;           // k5 blocks: 1 pair per wave

    // Workspace layout (z16 aliases hist/partition scratch, dead by k5)
    char* ws = (char*)d_ws;
    auto al16 = [](size_t x) { return (x + 15) & ~15ull; };
    ushort* msg16   = (ushort*)ws;  ws += al16((size_t)N * D * 2);
    int*    offsets = (int*)ws;     ws += al16((size_t)(N + 1) * 4);
    int*    tot     = (int*)ws;     ws += al16(256 * 4);
    ushort* sortedG = (ushort*)ws;  ws += al16((size_t)E * 2);
    // overlap region: max(histG+startG+packedG, z16)
    ushort* z16     = (ushort*)ws;                     // N*D bf16 (6.4 MB)
    int*    histG   = (int*)ws;                        // NBA*256 ints
    int*    startG  = histG + (size_t)NBA * 256;       // NBA*256 ints
    uint*   packedG = (uint*)(startG + (size_t)NBA * 256);  // E uints

    // 1) fused: message MLP (MFMA) + per-chunk bucket histogram
    kA_mlp_hist<<<NBA + MB, 256, 0, stream>>>(
        y, W1, b1, W2, b2, msg16, N, dst, histG, E, NBA);

    // 2) per-bucket scan over chunk histograms
    kB_scan<<<256, 256, 0, stream>>>(histG, startG, tot, NBA);

    // 3) partition edges into bucket-grouped packedG
    kC_partition<<<NBA, 256, 0, stream>>>(src, dst, startG, tot, packedG, E);

    // 4) per-bucket counting sort (LDS-staged) -> sortedG + offsets
    kF_place<<<NBUCK, 256, 0, stream>>>(packedG, tot, sortedG, offsets, N, E);

    // 5) gather segment-sum -> z16 (2 nodes per wave)
    k5_gather<<<G5, 256, 0, stream>>>(msg16, offsets, sortedG, z16, N);

    // 6) update MLP (MFMA) -> out
    k_mlp2<<<MB, 256, 0, stream>>>(z16, U1, c1, U2, c2, (float*)d_out, N);
}

// Round 11
// 140.906 us; speedup vs baseline: 1.4035x; 1.0582x over previous
//
#include <hip/hip_runtime.h>

#define D 64
#define CHUNK 4096      // edges per partition block
#define BSHIFT 8        // bucket = dst >> 8 (256 nodes per bucket)
#define MAXB 8192       // max edges per bucket for LDS-staged sort

typedef unsigned int uint;
typedef unsigned short ushort;

using bf16x8 = __attribute__((ext_vector_type(8))) short;   // 8 bf16 (4 VGPRs)
using f32x4  = __attribute__((ext_vector_type(4))) float;   // 4 fp32 acc

// fp32 -> bf16 round-to-nearest-even (finite inputs)
__device__ __forceinline__ uint f2bf(float f) {
    uint u = __float_as_uint(f);
    return (u + 0x7fffu + ((u >> 16) & 1u)) >> 16;
}
__device__ __forceinline__ uint pk2(float a, float b) {
    return f2bf(a) | (f2bf(b) << 16);
}

// masked accumulate: acc += mk * decode(v)  (uint4 = 8 packed bf16)
#define ACC8M(v, aE, aO, mk) do {                                              \
    aE[0] = fmaf(mk, __uint_as_float((v).x << 16), aE[0]);                     \
    aO[0] = fmaf(mk, __uint_as_float((v).x & 0xffff0000u), aO[0]);             \
    aE[1] = fmaf(mk, __uint_as_float((v).y << 16), aE[1]);                     \
    aO[1] = fmaf(mk, __uint_as_float((v).y & 0xffff0000u), aO[1]);             \
    aE[2] = fmaf(mk, __uint_as_float((v).z << 16), aE[2]);                     \
    aO[2] = fmaf(mk, __uint_as_float((v).z & 0xffff0000u), aO[2]);             \
    aE[3] = fmaf(mk, __uint_as_float((v).w << 16), aE[3]);                     \
    aO[3] = fmaf(mk, __uint_as_float((v).w & 0xffff0000u), aO[3]);             \
} while (0)

// ---------------------------------------------------------------------------
// MFMA 2-layer MLP tile with PRE-PACKED bf16 weights: 16 coalesced 16B frag
// loads (L1-hot) replace 128 scalar loads + 128 converts per wave.
// Pack layout: pk[((t*2+kf)*64 + lane)*8 + j] = bf16(W[(kf*32+q*8+j)*D + t*16+m])
//   A-frag:  lane holds A[m=lane&15][k=quad*8+j]
//   B-frag:  lane holds B[k=quad*8+j][n=lane&15]
//   C/D:     lane holds D[row=quad*4+reg][col=lane&15]
// ---------------------------------------------------------------------------
template <bool BF16IN, bool BF16OUT>
__device__ __forceinline__ void mlp_tile(
    int tile, ushort (*Hs)[72],
    const float* __restrict__ Xf, const ushort* __restrict__ Xb,
    const ushort* __restrict__ pkW1, const float* __restrict__ b1v,
    const ushort* __restrict__ pkW2, const float* __restrict__ b2v,
    ushort* __restrict__ out16, float* __restrict__ out32, int N)
{
    const int lane = threadIdx.x & 63;
    const int m = lane & 15;
    const int q = lane >> 4;

    // weight B-frags: 16B vector loads from frag-packed tables
    bf16x8 w1f[4][2], w2f[4][2];
    #pragma unroll
    for (int t = 0; t < 4; ++t) {
        #pragma unroll
        for (int kf = 0; kf < 2; ++kf) {
            const int off = ((t * 2 + kf) * 64 + lane) << 3;
            w1f[t][kf] = *(const bf16x8*)(pkW1 + off);
            w2f[t][kf] = *(const bf16x8*)(pkW2 + off);
        }
    }

    // X A-frags
    const int rowbase = tile * 16;
    int r = rowbase + m;
    if (r >= N) r = N - 1;               // clamp loads; stores predicated
    bf16x8 ax0, ax1;
    if (BF16IN) {
        const ushort* xr = Xb + (size_t)r * D + q * 8;
        ax0 = *(const bf16x8*)xr;
        ax1 = *(const bf16x8*)(xr + 32);
    } else {
        const float* xr = Xf + (size_t)r * D + q * 8;
        float4 x0 = *(const float4*)xr;
        float4 x1 = *(const float4*)(xr + 4);
        float4 x2 = *(const float4*)(xr + 32);
        float4 x3 = *(const float4*)(xr + 36);
        ax0[0]=(short)f2bf(x0.x); ax0[1]=(short)f2bf(x0.y);
        ax0[2]=(short)f2bf(x0.z); ax0[3]=(short)f2bf(x0.w);
        ax0[4]=(short)f2bf(x1.x); ax0[5]=(short)f2bf(x1.y);
        ax0[6]=(short)f2bf(x1.z); ax0[7]=(short)f2bf(x1.w);
        ax1[0]=(short)f2bf(x2.x); ax1[1]=(short)f2bf(x2.y);
        ax1[2]=(short)f2bf(x2.z); ax1[3]=(short)f2bf(x2.w);
        ax1[4]=(short)f2bf(x3.x); ax1[5]=(short)f2bf(x3.y);
        ax1[6]=(short)f2bf(x3.z); ax1[7]=(short)f2bf(x3.w);
    }

    const f32x4 zero4 = {0.f, 0.f, 0.f, 0.f};
    f32x4 acc[4];

    // layer 1
    #pragma unroll
    for (int t = 0; t < 4; ++t) acc[t] = zero4;
    #pragma unroll
    for (int t = 0; t < 4; ++t) {
        acc[t] = __builtin_amdgcn_mfma_f32_16x16x32_bf16(ax0, w1f[t][0], acc[t], 0, 0, 0);
        acc[t] = __builtin_amdgcn_mfma_f32_16x16x32_bf16(ax1, w1f[t][1], acc[t], 0, 0, 0);
    }
    #pragma unroll
    for (int t = 0; t < 4; ++t) {
        const float bv = b1v[t * 16 + m];
        #pragma unroll
        for (int rg = 0; rg < 4; ++rg) {
            float hv = fmaxf(acc[t][rg] + bv, 0.f);
            Hs[q * 4 + rg][t * 16 + m] = (ushort)f2bf(hv);
        }
    }
    __syncthreads();

    // H C-layout -> A-frags
    bf16x8 ah0 = *(const bf16x8*)&Hs[m][q * 8];
    bf16x8 ah1 = *(const bf16x8*)&Hs[m][32 + q * 8];

    // layer 2
    #pragma unroll
    for (int t = 0; t < 4; ++t) acc[t] = zero4;
    #pragma unroll
    for (int t = 0; t < 4; ++t) {
        acc[t] = __builtin_amdgcn_mfma_f32_16x16x32_bf16(ah0, w2f[t][0], acc[t], 0, 0, 0);
        acc[t] = __builtin_amdgcn_mfma_f32_16x16x32_bf16(ah1, w2f[t][1], acc[t], 0, 0, 0);
    }
    #pragma unroll
    for (int t = 0; t < 4; ++t) {
        const float bv = b2v[t * 16 + m];
        #pragma unroll
        for (int rg = 0; rg < 4; ++rg) {
            const int row = rowbase + q * 4 + rg;
            if (row < N) {
                float ov = fmaxf(acc[t][rg] + bv, 0.f);
                if (BF16OUT) out16[(size_t)row * D + t * 16 + m] = (ushort)f2bf(ov);
                else         out32[(size_t)row * D + t * 16 + m] = ov;
            }
        }
    }
}

// ---------------------------------------------------------------------------
// kA: blocks [0,NBA): per-chunk bucket histogram (LDS only, int4-batched)
//     blocks [NBA, NBA+4): pack weight matrix (W1/W2/U1/U2) into frag order.
// ---------------------------------------------------------------------------
__global__ __launch_bounds__(256) void kA_hist_pack(
    const int* __restrict__ dst, int* __restrict__ histG, int E, int NBA,
    const float* __restrict__ W1, const float* __restrict__ W2,
    const float* __restrict__ U1, const float* __restrict__ U2,
    ushort* __restrict__ pkAll)
{
    __shared__ int lhist[256];
    const int t = threadIdx.x;
    if ((int)blockIdx.x < NBA) {
        lhist[t] = 0;
        __syncthreads();
        const int cbase = blockIdx.x * CHUNK;
        const int lim = min(CHUNK, E - cbase);
        if (lim == CHUNK) {
            const int4* dp = (const int4*)(dst + cbase);
            int4 d4[4];
            #pragma unroll
            for (int g = 0; g < 4; ++g) d4[g] = dp[g * 256 + t];
            #pragma unroll
            for (int g = 0; g < 4; ++g) {
                atomicAdd(&lhist[(uint)d4[g].x >> BSHIFT], 1);
                atomicAdd(&lhist[(uint)d4[g].y >> BSHIFT], 1);
                atomicAdd(&lhist[(uint)d4[g].z >> BSHIFT], 1);
                atomicAdd(&lhist[(uint)d4[g].w >> BSHIFT], 1);
            }
        } else {
            for (int j = t; j < lim; j += 256)
                atomicAdd(&lhist[(uint)dst[cbase + j] >> BSHIFT], 1);
        }
        __syncthreads();
        histG[blockIdx.x * 256 + t] = lhist[t];
    } else {
        const int mtx = blockIdx.x - NBA;                // 0..3
        const float* W = (mtx == 0) ? W1 : (mtx == 1) ? W2 : (mtx == 2) ? U1 : U2;
        ushort* pk = pkAll + mtx * 4096;
        for (int u = t; u < 512; u += 256) {             // u = (t_,kf,lane)
            const int t_ = u >> 7;
            const int rem = u & 127;
            const int kf = rem >> 6;
            const int lane = rem & 63;
            const int q = lane >> 4, m = lane & 15;
            const int n = t_ * 16 + m;
            uint w[4];
            #pragma unroll
            for (int j2 = 0; j2 < 4; ++j2) {
                const int k = kf * 32 + q * 8 + 2 * j2;
                w[j2] = pk2(W[k * D + n], W[(k + 1) * D + n]);
            }
            uint4 v = { w[0], w[1], w[2], w[3] };
            *(uint4*)(pk + (u << 3)) = v;
        }
    }
}

// ---------------------------------------------------------------------------
// kB: one block per bucket: exclusive scan over the NBA chunk histograms
//     -> startG[(chunk,bucket)], tot[bucket]. Generic in NBA (<=2048).
// ---------------------------------------------------------------------------
__global__ __launch_bounds__(256) void kB_scan(
    const int* __restrict__ histG, int* __restrict__ startG,
    int* __restrict__ tot, int NBA)
{
    __shared__ int tmp[256];
    const int t = threadIdx.x;
    const int b = blockIdx.x;
    const int K = (NBA + 255) / 256;     // chunks per thread (<=8)
    const int c0 = t * K;
    int loc[8];
    int s = 0;
    #pragma unroll
    for (int i = 0; i < 8; ++i) {
        if (i < K) {
            const int c = c0 + i;
            loc[i] = s;
            s += (c < NBA) ? histG[c * 256 + b] : 0;
        }
    }
    int x = s; tmp[t] = x; __syncthreads();
    #pragma unroll
    for (int off = 1; off < 256; off <<= 1) {
        int add = (t >= off) ? tmp[t - off] : 0; __syncthreads();
        x += add; tmp[t] = x; __syncthreads();
    }
    const int base = x - s;
    #pragma unroll
    for (int i = 0; i < 8; ++i) {
        if (i < K) {
            const int c = c0 + i;
            if (c < NBA) startG[c * 256 + b] = base + loc[i];
        }
    }
    if (t == 255) tot[b] = x;
}

// ---------------------------------------------------------------------------
// kC: blocks [0,NBA): partition edges into bucket-grouped packedG
//     blocks [NBA,...): message MLP (MFMA, packed weights) y -> msg16 bf16.
// ---------------------------------------------------------------------------
__global__ __launch_bounds__(256) void kC_part_mlp1(
    const int* __restrict__ src, const int* __restrict__ dst,
    const int* __restrict__ startG, const int* __restrict__ tot,
    uint* __restrict__ packedG, int E, int NBA,
    const float* __restrict__ y, const ushort* __restrict__ pkAll,
    const float* __restrict__ b1, const float* __restrict__ b2,
    ushort* __restrict__ msg16, int N)
{
    __shared__ int t1[256];
    __shared__ int cur[256];
    __shared__ __align__(16) ushort Hs[4][16][72];
    const int t = threadIdx.x;
    if ((int)blockIdx.x < NBA) {
        int tv = tot[t];
        int x = tv; t1[t] = x; __syncthreads();
        #pragma unroll
        for (int off = 1; off < 256; off <<= 1) {
            int add = (t >= off) ? t1[t - off] : 0; __syncthreads();
            x += add; t1[t] = x; __syncthreads();
        }
        cur[t] = (x - tv) + startG[blockIdx.x * 256 + t];
        __syncthreads();
        const int cbase = blockIdx.x * CHUNK;
        const int lim = min(CHUNK, E - cbase);
        if (lim == CHUNK) {
            const int4* sp = (const int4*)(src + cbase);
            const int4* dp = (const int4*)(dst + cbase);
            int4 s4[4], d4[4];
            #pragma unroll
            for (int g = 0; g < 4; ++g) { s4[g] = sp[g * 256 + t]; d4[g] = dp[g * 256 + t]; }
            #pragma unroll
            for (int g = 0; g < 4; ++g) {
                int pos;
                pos = atomicAdd(&cur[(uint)d4[g].x >> BSHIFT], 1);
                packedG[pos] = ((uint)(d4[g].x & 255) << 16) | (uint)s4[g].x;
                pos = atomicAdd(&cur[(uint)d4[g].y >> BSHIFT], 1);
                packedG[pos] = ((uint)(d4[g].y & 255) << 16) | (uint)s4[g].y;
                pos = atomicAdd(&cur[(uint)d4[g].z >> BSHIFT], 1);
                packedG[pos] = ((uint)(d4[g].z & 255) << 16) | (uint)s4[g].z;
                pos = atomicAdd(&cur[(uint)d4[g].w >> BSHIFT], 1);
                packedG[pos] = ((uint)(d4[g].w & 255) << 16) | (uint)s4[g].w;
            }
        } else {
            for (int j = t; j < lim; j += 256) {
                const int e = cbase + j;
                int s = src[e], d = dst[e];
                int pos = atomicAdd(&cur[(uint)d >> BSHIFT], 1);
                packedG[pos] = ((uint)(d & 255) << 16) | (uint)s;
            }
        }
    } else {
        const int tile = (blockIdx.x - NBA) * 4 + (t >> 6);
        mlp_tile<false, true>(tile, Hs[t >> 6], y, nullptr,
                              pkAll + 0 * 4096, b1, pkAll + 1 * 4096, b2,
                              msg16, nullptr, N);
    }
}

// ---------------------------------------------------------------------------
// kF: one block per bucket. Stage the bucket's packedG region in LDS once
// (coalesced read), count+scan+place in LDS, write sortedG coalesced.
// Fallback to the global 2-pass path if the bucket exceeds MAXB.
// ---------------------------------------------------------------------------
__global__ __launch_bounds__(256) void kF_place(
    const uint* __restrict__ packedG, const int* __restrict__ tot,
    ushort* __restrict__ sortedG, int* __restrict__ offsets, int N, int E)
{
    __shared__ int t1[256];
    __shared__ int cnt[256];
    __shared__ int cur[256];
    __shared__ uint pk[MAXB];      // 32 KB
    __shared__ ushort srt[MAXB];   // 16 KB
    const int t = threadIdx.x;
    const int b = blockIdx.x;

    int tv = tot[t];
    int x = tv; t1[t] = x; __syncthreads();
    #pragma unroll
    for (int off = 1; off < 256; off <<= 1) {
        int add = (t >= off) ? t1[t - off] : 0; __syncthreads();
        x += add; t1[t] = x; __syncthreads();
    }
    const int pbase = (b == 0) ? 0 : t1[b - 1];
    const int cn = tot[b];
    const bool fits = (cn <= MAXB);

    cnt[t] = 0;
    __syncthreads();
    if (fits) {
        for (int i = t; i < cn; i += 256) pk[i] = packedG[pbase + i];
        __syncthreads();
        for (int i = t; i < cn; i += 256) atomicAdd(&cnt[pk[i] >> 16], 1);
    } else {
        for (int i = t; i < cn; i += 256)
            atomicAdd(&cnt[packedG[pbase + i] >> 16], 1);
    }
    __syncthreads();

    int c = cnt[t];
    int x2 = c; t1[t] = x2; __syncthreads();
    #pragma unroll
    for (int off = 1; off < 256; off <<= 1) {
        int add = (t >= off) ? t1[t - off] : 0; __syncthreads();
        x2 += add; t1[t] = x2; __syncthreads();
    }
    const int excl = x2 - c;
    const int node = b * 256 + t;
    if (node < N) offsets[node] = pbase + excl;
    if (b == 0 && t == 0) offsets[N] = E;

    if (fits) {
        cur[t] = excl;                       // local positions
        __syncthreads();
        for (int i = t; i < cn; i += 256) {
            uint e = pk[i];
            int p = atomicAdd(&cur[e >> 16], 1);
            srt[p] = (ushort)(e & 0xffffu);
        }
        __syncthreads();
        for (int i = t; i < cn; i += 256)    // coalesced write-out
            sortedG[pbase + i] = srt[i];
    } else {
        cur[t] = pbase + excl;
        __syncthreads();
        for (int i = t; i < cn; i += 256) {
            uint e = packedG[pbase + i];
            int p = atomicAdd(&cur[e >> 16], 1);
            sortedG[p] = (ushort)(e & 0xffffu);
        }
    }
}

// ---------------------------------------------------------------------------
// k5: gather segment-sum (bf16 msg) -> z bf16. TWO nodes per wave:
//   sub=lane&7 (16B slice), grp=(lane>>3)&3 (edge), half=lane>>5 (node).
// Up to 8 steps (32 edges/node) issued fully before any decode; masked fma
// tails; outer loop covers deg>32.
// ---------------------------------------------------------------------------
__global__ __launch_bounds__(256, 6) void k5_gather(
    const ushort* __restrict__ msg16,
    const int* __restrict__ offsets, const ushort* __restrict__ sortedG,
    ushort* __restrict__ z16, int n_nodes)
{
    const int lane = threadIdx.x & 63;
    const int sub = lane & 7;
    const int grp = (lane >> 3) & 3;
    const int half = lane >> 5;
    const int p = blockIdx.x * 4 + (threadIdx.x >> 6);   // pair index
    if (p * 2 >= n_nodes) return;
    const ushort* mbase = msg16 + (sub << 3);

    const int n = 2 * p + half;                          // per-lane node
    const bool nvalid = n < n_nodes;
    int beg = 0, end = 0;
    if (nvalid) { beg = offsets[n]; end = offsets[n + 1]; }
    const int m = end - beg;
    const int m0 = __builtin_amdgcn_readfirstlane(m);    // half0 degree
    const int m1 = __builtin_amdgcn_readlane(m, 32);     // half1 degree
    const int mmax = max(m0, m1);                        // wave-uniform

    float aE[4] = {0, 0, 0, 0}, aO[4] = {0, 0, 0, 0};

    for (int base = 0; base < mmax; base += 32) {
        int s[8];
        float mk[8];
        #pragma unroll
        for (int j = 0; j < 8; ++j) {
            if (base + j * 4 < mmax) {                   // uniform guard
                const int e = base + j * 4 + grp;
                const bool on = (e < m);                 // per-lane mask
                mk[j] = on ? 1.f : 0.f;
                s[j] = (int)sortedG[on ? (beg + e) : 0];
            }
        }
        uint4 v[8];
        #pragma unroll
        for (int j = 0; j < 8; ++j)                      // all rows in flight
            if (base + j * 4 < mmax)
                v[j] = *(const uint4*)(mbase + ((size_t)s[j] << 6));
        #pragma unroll
        for (int j = 0; j < 8; ++j)
            if (base + j * 4 < mmax) { ACC8M(v[j], aE, aO, mk[j]); }
    }

    #pragma unroll
    for (int d2 = 0; d2 < 4; ++d2) {   // reduce over grp (lane bits 3,4 only)
        aE[d2] += __shfl_xor(aE[d2], 8, 64);
        aO[d2] += __shfl_xor(aO[d2], 8, 64);
        aE[d2] += __shfl_xor(aE[d2], 16, 64);
        aO[d2] += __shfl_xor(aO[d2], 16, 64);
    }
    if (grp == 0 && nvalid) {          // lanes 0-7 & 32-39: 16B each
        uint4 pv;
        pv.x = pk2(aE[0], aO[0]);
        pv.y = pk2(aE[1], aO[1]);
        pv.z = pk2(aE[2], aO[2]);
        pv.w = pk2(aE[3], aO[3]);
        *(uint4*)(z16 + (size_t)n * D + (sub << 3)) = pv;
    }
}

// ---------------------------------------------------------------------------
// mlp2: update MLP (MFMA, packed weights): z16 bf16 -> out fp32
// ---------------------------------------------------------------------------
__global__ __launch_bounds__(256) void k_mlp2(
    const ushort* __restrict__ z16, const ushort* __restrict__ pkAll,
    const float* __restrict__ c1, const float* __restrict__ c2,
    float* __restrict__ out, int N)
{
    __shared__ __align__(16) ushort Hs[4][16][72];
    const int tile = blockIdx.x * 4 + (threadIdx.x >> 6);
    mlp_tile<true, false>(tile, Hs[threadIdx.x >> 6], nullptr, z16,
                          pkAll + 2 * 4096, c1, pkAll + 3 * 4096, c2,
                          nullptr, out, N);
}

extern "C" void kernel_launch(void* const* d_in, const int* in_sizes, int n_in,
                              void* d_out, int out_size, void* d_ws, size_t ws_size,
                              hipStream_t stream) {
    const float* y  = (const float*)d_in[0];
    const int*  src = (const int*) d_in[1];
    const int*  dst = (const int*) d_in[2];
    const float* W1 = (const float*)d_in[3];
    const float* b1 = (const float*)d_in[4];
    const float* W2 = (const float*)d_in[5];
    const float* b2 = (const float*)d_in[6];
    const float* U1 = (const float*)d_in[7];
    const float* c1 = (const float*)d_in[8];
    const float* U2 = (const float*)d_in[9];
    const float* c2 = (const float*)d_in[10];

    const int N = in_sizes[0] / D;               // 50000
    const int E = in_sizes[1];                   // 1250000
    const int NBA   = (E + CHUNK - 1) / CHUNK;   // 306 partition chunks
    const int NBUCK = (N + 255) / 256;           // 196 buckets
    const int NT    = (N + 15) / 16;             // 3125 MFMA row-tiles
    const int MB    = (NT + 3) / 4;              // 782 MLP blocks
    const int G5    = (N / 2 + 3) / 4;           // k5 blocks: 1 pair per wave

    // Workspace layout (z16 aliases hist/partition scratch, dead by k5)
    char* ws = (char*)d_ws;
    auto al16 = [](size_t x) { return (x + 15) & ~15ull; };
    ushort* msg16   = (ushort*)ws;  ws += al16((size_t)N * D * 2);
    int*    offsets = (int*)ws;     ws += al16((size_t)(N + 1) * 4);
    int*    tot     = (int*)ws;     ws += al16(256 * 4);
    ushort* sortedG = (ushort*)ws;  ws += al16((size_t)E * 2);
    ushort* pkAll   = (ushort*)ws;  ws += al16(4 * 4096 * 2);   // packed weights
    // overlap region: max(histG+startG+packedG, z16)
    ushort* z16     = (ushort*)ws;                     // N*D bf16 (6.4 MB)
    int*    histG   = (int*)ws;                        // NBA*256 ints
    int*    startG  = histG + (size_t)NBA * 256;       // NBA*256 ints
    uint*   packedG = (uint*)(startG + (size_t)NBA * 256);  // E uints

    // 1) per-chunk bucket histogram + weight pre-pack (bf16 frag order)
    kA_hist_pack<<<NBA + 4, 256, 0, stream>>>(
        dst, histG, E, NBA, W1, W2, U1, U2, pkAll);

    // 2) per-bucket scan over chunk histograms
    kB_scan<<<NBUCK > 256 ? NBUCK : 256, 256, 0, stream>>>(histG, startG, tot, NBA);

    // 3) partition edges into packedG + message MLP (overlapped)
    kC_part_mlp1<<<NBA + MB, 256, 0, stream>>>(
        src, dst, startG, tot, packedG, E, NBA,
        y, pkAll, b1, b2, msg16, N);

    // 4) per-bucket counting sort (LDS-staged) -> sortedG + offsets
    kF_place<<<NBUCK, 256, 0, stream>>>(packedG, tot, sortedG, offsets, N, E);

    // 5) gather segment-sum -> z16 (2 nodes per wave)
    k5_gather<<<G5, 256, 0, stream>>>(msg16, offsets, sortedG, z16, N);

    // 6) update MLP (MFMA) -> out
    k_mlp2<<<MB, 256, 0, stream>>>(z16, pkAll, c1, c2, (float*)d_out, N);
}